// Round 8
// baseline (449.574 us; speedup 1.0000x reference)
//
#include <hip/hip_runtime.h>
#include <hip/hip_bf16.h>
#include <math.h>

#define EMBED   256
#define KDIM    512
#define BATCH   256
#define BM      128
#define BN      128

typedef float  f32x4   __attribute__((ext_vector_type(4)));
typedef __bf16 bf16x8  __attribute__((ext_vector_type(8)));
typedef unsigned short ushort8 __attribute__((ext_vector_type(8)));

__device__ __forceinline__ unsigned short f2h(float f) {
    unsigned int u = __float_as_uint(f);
    u += 0x7FFFu + ((u >> 16) & 1u);
    return (unsigned short)(u >> 16);
}
__device__ __forceinline__ float h2f(unsigned short h) {
    return __uint_as_float(((unsigned int)h) << 16);
}
// async global->LDS, 16B/lane; LDS dest = wave-uniform base + lane*16
__device__ __forceinline__ void gload16(const void* g, void* l) {
    __builtin_amdgcn_global_load_lds(
        (const __attribute__((address_space(1))) unsigned int*)g,
        (__attribute__((address_space(3))) unsigned int*)l, 16, 0, 0);
}

// ---------------- main tree GEMM (levels 1..5) ----------------
// m97 structure: 256 thr / 4 waves, block 128x128 (2 col-blocks), wave 64x64,
// acc 4x4, BK=32, SINGLE-buffer LDS (32KB -> ~3 blocks/CU), 2-barrier K-loop.
// Split-bf16 hi/lo, 3 MFMA passes: hh, hl (Ah*Bl), lh (Al*Bh).
template<int LV1, int WPREP>
__global__ __launch_bounds__(256) void gemm_tree(
    const unsigned short* __restrict__ Xh, const unsigned short* __restrict__ Xl,
    const unsigned short* __restrict__ Wh, const unsigned short* __restrict__ Wl,
    const float*  __restrict__ Wf,
    const float*  __restrict__ bias,
    unsigned short* __restrict__ Yh, unsigned short* __restrict__ Yl,
    const int* __restrict__ tok, const float* __restrict__ emb)
{
    // fragment-order LDS: subtile s = 16 rows x 32 k = 512 ushort at s*512, lane slot l*8
    __shared__ __align__(16) unsigned short AhL[4096], AlL[4096];   // 128 x 32 hi/lo
    __shared__ __align__(16) unsigned short BhL[4096], BlL[4096];   // 128 x 32 hi/lo

    const int tid = threadIdx.x;
    const int w   = tid >> 6;          // 0..3
    const int l   = tid & 63;
    const int q   = l >> 4;
    const int rr  = l & 15;

    // XCD-chunked swizzle (nwg % 8 == 0 at every level); the two col-halves of
    // the same row-block are adjacent in a chunk -> same-XCD L2 reuse of A.
    const int nwg = gridDim.x;
    const int bid = blockIdx.x;
    const int swz = (bid & 7) * (nwg >> 3) + (bid >> 3);
    const int m0  = (swz >> 1) * BM;
    const int n0  = (swz & 1) * BN;

    const int waveM = w >> 1;          // 0..1 -> rows waveM*64..
    const int waveN = w & 1;           // 0..1 -> cols waveN*64..

    int tk[2][2];
    if constexpr (LV1) {
        #pragma unroll
        for (int g = 0; g < 2; ++g) {
            const int r = m0 + (w + g * 4) * 16 + rr;
            tk[g][0] = tok[2 * r];
            tk[g][1] = tok[2 * r + 1];
        }
    }

    f32x4 acc[4][4] = {};              // 4 M-frags x 4 N-frags x 4 f32

    for (int t = 0; t < 16; ++t) {
        const int k0   = t << 5;
        const int joff = k0 >> 8;              // which of the concat pair
        const int c    = (k0 & 255) + q * 8;   // col within source row

        // ---- stage A: wave w owns subtiles {w, w+4} ----
        if constexpr (LV1) {
            #pragma unroll
            for (int g = 0; g < 2; ++g) {
                const int s = w + g * 4;
                const float* e = emb + (size_t)tk[g][joff] * EMBED + c;
                float v[8];
                *(float4*)&v[0] = *(const float4*)e;
                *(float4*)&v[4] = *(const float4*)(e + 4);
                ushort8 hs, ls;
                #pragma unroll
                for (int i = 0; i < 8; ++i) {
                    const float f = fmaxf(v[i], 0.f);
                    const unsigned short h = f2h(f);
                    hs[i] = h;
                    ls[i] = f2h(f - h2f(h));
                }
                *(ushort8*)&AhL[s * 512 + l * 8] = hs;
                *(ushort8*)&AlL[s * 512 + l * 8] = ls;
            }
        } else {
            #pragma unroll
            for (int g = 0; g < 2; ++g) {
                const int s = w + g * 4;
                const size_t off = (size_t)(2 * (m0 + s * 16 + rr) + joff) * EMBED + c;
                gload16(Xh + off, &AhL[s * 512]);
                gload16(Xl + off, &AlL[s * 512]);
            }
        }

        // ---- stage B: wave w owns subtiles {w, w+4} ----
        #pragma unroll
        for (int g = 0; g < 2; ++g) {
            const int s = w + g * 4;
            if constexpr (WPREP) {
                const size_t off = (size_t)(n0 + s * 16 + rr) * KDIM + k0 + q * 8;
                gload16(Wh + off, &BhL[s * 512]);
                gload16(Wl + off, &BlL[s * 512]);
            } else {
                const float* ws = Wf + (size_t)(n0 + s * 16 + rr) * KDIM + k0 + q * 8;
                float v[8];
                *(float4*)&v[0] = *(const float4*)ws;
                *(float4*)&v[4] = *(const float4*)(ws + 4);
                ushort8 hs, ls;
                #pragma unroll
                for (int i = 0; i < 8; ++i) {
                    const unsigned short h = f2h(v[i]);
                    hs[i] = h;
                    ls[i] = f2h(v[i] - h2f(h));
                }
                *(ushort8*)&BhL[s * 512 + l * 8] = hs;
                *(ushort8*)&BlL[s * 512 + l * 8] = ls;
            }
        }

        __syncthreads();   // staged tile visible (drains vmcnt+lgkmcnt)

        // ---- 3-pass split MFMA; x0 reused for Bl then Al to cap liveness ----
        bf16x8 a0[4], b0[4], x0[4];
        #pragma unroll
        for (int mi = 0; mi < 4; ++mi)
            a0[mi] = *(const bf16x8*)&AhL[(waveM * 4 + mi) * 512 + l * 8];
        #pragma unroll
        for (int ni = 0; ni < 4; ++ni)
            b0[ni] = *(const bf16x8*)&BhL[(waveN * 4 + ni) * 512 + l * 8];
        #pragma unroll
        for (int mi = 0; mi < 4; ++mi)
            #pragma unroll
            for (int ni = 0; ni < 4; ++ni)
                acc[mi][ni] = __builtin_amdgcn_mfma_f32_16x16x32_bf16(a0[mi], b0[ni], acc[mi][ni], 0, 0, 0);

        #pragma unroll
        for (int ni = 0; ni < 4; ++ni)
            x0[ni] = *(const bf16x8*)&BlL[(waveN * 4 + ni) * 512 + l * 8];
        #pragma unroll
        for (int mi = 0; mi < 4; ++mi)
            #pragma unroll
            for (int ni = 0; ni < 4; ++ni)
                acc[mi][ni] = __builtin_amdgcn_mfma_f32_16x16x32_bf16(a0[mi], x0[ni], acc[mi][ni], 0, 0, 0);

        #pragma unroll
        for (int mi = 0; mi < 4; ++mi)
            x0[mi] = *(const bf16x8*)&AlL[(waveM * 4 + mi) * 512 + l * 8];
        #pragma unroll
        for (int mi = 0; mi < 4; ++mi)
            #pragma unroll
            for (int ni = 0; ni < 4; ++ni)
                acc[mi][ni] = __builtin_amdgcn_mfma_f32_16x16x32_bf16(x0[mi], b0[ni], acc[mi][ni], 0, 0, 0);

        __syncthreads();   // all reads done before next-step overwrite
    }

    // ---- epilogue: bias + relu + hi/lo split store (C/D: col=l&15, row=(l>>4)*4+jj) ----
    #pragma unroll
    for (int ni = 0; ni < 4; ++ni) {
        const int col = n0 + waveN * 64 + ni * 16 + rr;
        const float bv = bias[col];
        #pragma unroll
        for (int mi = 0; mi < 4; ++mi) {
            const int row0 = m0 + waveM * 64 + mi * 16 + q * 4;
            #pragma unroll
            for (int jj = 0; jj < 4; ++jj) {
                const float y = fmaxf(acc[mi][ni][jj] + bv, 0.f);
                const unsigned short h = f2h(y);
                Yh[(size_t)(row0 + jj) * EMBED + col] = h;
                Yl[(size_t)(row0 + jj) * EMBED + col] = f2h(y - h2f(h));
            }
        }
    }
}

// ---------------- fused tail: levels 6..10 + head, one block per batch element ----------------
template<int WPREP>
__global__ __launch_bounds__(256) void tail_kernel(
    const unsigned short* __restrict__ Xh5, const unsigned short* __restrict__ Xl5,
    const unsigned short* __restrict__ Wh, const unsigned short* __restrict__ Wl,
    const float* __restrict__ Wf, const float* __restrict__ bias,
    const float* __restrict__ Pw, const float* __restrict__ Pb,
    const int* __restrict__ labels, float* __restrict__ out)
{
    // X buffers: row-major [rows][256] hi/lo, XOR-swizzled (ushort idx ^= (row&7)<<3)
    __shared__ __align__(16) unsigned short X0h[8192], X0l[8192];   // 32 rows
    __shared__ __align__(16) unsigned short X1h[4096], X1l[4096];   // 16 rows
    __shared__ __align__(16) unsigned short BhT[2][8192], BlT[2][8192];

    const int tid = threadIdx.x;
    const int w   = tid >> 6;      // 0..3
    const int l   = tid & 63;
    const int q   = l >> 4;
    const int rr  = l & 15;
    const int b   = blockIdx.x;

    // init X0 from level-5 output (swizzled ds_write; gload_lds can't swizzle)
    {
        const int row = tid >> 3;             // 0..31
        const int c0  = (tid & 7) * 32;
        #pragma unroll
        for (int i = 0; i < 4; ++i) {
            const int col = c0 + i * 8;
            const int sw  = (row * 256 + col) ^ ((row & 7) << 3);
            *(ushort8*)&X0h[sw] = *(const ushort8*)&Xh5[(size_t)(b * 32 + row) * EMBED + col];
            *(ushort8*)&X0l[sw] = *(const ushort8*)&Xl5[(size_t)(b * 32 + row) * EMBED + col];
        }
    }

    auto stageB = [&](int buf, int k0) {
        if constexpr (WPREP) {
            #pragma unroll
            for (int j = 0; j < 8; ++j) {
                const int sb = w * 8 + j;          // 0..31
                const int s  = sb & 15;
                const size_t off = (size_t)(s * 16 + rr) * KDIM + k0 + q * 8;
                if (sb < 16) gload16(Wh + off, &BhT[buf][s * 512]);
                else         gload16(Wl + off, &BlT[buf][s * 512]);
            }
        } else {
            #pragma unroll
            for (int j = 0; j < 4; ++j) {
                const int u = w * 4 + j;           // 0..15
                const float* ws = Wf + (size_t)(u * 16 + rr) * KDIM + k0 + q * 8;
                float v[8];
                *(float4*)&v[0] = *(const float4*)ws;
                *(float4*)&v[4] = *(const float4*)(ws + 4);
                ushort8 hs, ls;
                #pragma unroll
                for (int i = 0; i < 8; ++i) {
                    const unsigned short h = f2h(v[i]);
                    hs[i] = h;
                    ls[i] = f2h(v[i] - h2f(h));
                }
                *(ushort8*)&BhT[buf][u * 512 + l * 8] = hs;
                *(ushort8*)&BlT[buf][u * 512 + l * 8] = ls;
            }
        }
    };

    float bv[4];
    #pragma unroll
    for (int ni = 0; ni < 4; ++ni) bv[ni] = bias[w * 64 + ni * 16 + rr];

    stageB(0, 0);
    __syncthreads();

    int g = 0;
    for (int lv = 0; lv < 5; ++lv) {
        unsigned short* srch = (lv & 1) ? X1h : X0h;
        unsigned short* srcl = (lv & 1) ? X1l : X0l;
        unsigned short* dsth = (lv & 1) ? X0h : X1h;
        unsigned short* dstl = (lv & 1) ? X0l : X1l;
        const int Mout = 16 >> lv;

        f32x4 acc[4] = {};
        for (int t = 0; t < 16; ++t, ++g) {
            const int cur = g & 1;
            if (g < 79) stageB(cur ^ 1, ((t + 1) & 15) * 32);

            const int k0   = t * 32;
            const int joff = k0 >> 8;
            const int c    = (k0 & 255) + q * 8;
            const int row  = 2 * rr + joff;      // A row (stale beyond valid: harmless)
            const int idx  = (row * 256 + c) ^ ((row & 7) << 3);
            const bf16x8 a_h = *(const bf16x8*)&srch[idx];
            const bf16x8 a_l = *(const bf16x8*)&srcl[idx];

            bf16x8 bh4[4], bl4[4];
            #pragma unroll
            for (int ni = 0; ni < 4; ++ni) {
                bh4[ni] = *(const bf16x8*)&BhT[cur][(w * 4 + ni) * 512 + l * 8];
                bl4[ni] = *(const bf16x8*)&BlT[cur][(w * 4 + ni) * 512 + l * 8];
            }
            #pragma unroll
            for (int ni = 0; ni < 4; ++ni)
                acc[ni] = __builtin_amdgcn_mfma_f32_16x16x32_bf16(a_h, bh4[ni], acc[ni], 0, 0, 0);
            #pragma unroll
            for (int ni = 0; ni < 4; ++ni)
                acc[ni] = __builtin_amdgcn_mfma_f32_16x16x32_bf16(a_l, bh4[ni], acc[ni], 0, 0, 0);
            #pragma unroll
            for (int ni = 0; ni < 4; ++ni)
                acc[ni] = __builtin_amdgcn_mfma_f32_16x16x32_bf16(a_h, bl4[ni], acc[ni], 0, 0, 0);

            __syncthreads();
        }

        // epilogue: store valid rows only
        #pragma unroll
        for (int ni = 0; ni < 4; ++ni) {
            const int col = w * 64 + ni * 16 + rr;
            #pragma unroll
            for (int jj = 0; jj < 4; ++jj) {
                const int row = q * 4 + jj;
                if (row < Mout) {
                    const float y = fmaxf(acc[ni][jj] + bv[ni], 0.f);
                    const unsigned short h = f2h(y);
                    const int idx = (row * 256 + col) ^ ((row & 7) << 3);
                    dsth[idx] = h;
                    dstl[idx] = f2h(y - h2f(h));
                }
            }
        }
        __syncthreads();
    }

    // head: root = X1 row 0 (swizzle is identity for row 0)
    if (w == 0) {
        float s0 = 0.f, s1 = 0.f;
        #pragma unroll
        for (int i = 0; i < 4; ++i) {
            const int col = l + i * 64;
            const float x = h2f(X1h[col]) + h2f(X1l[col]);
            s0 = fmaf(x, Pw[col], s0);
            s1 = fmaf(x, Pw[EMBED + col], s1);
        }
        #pragma unroll
        for (int off = 32; off > 0; off >>= 1) {
            s0 += __shfl_down(s0, off);
            s1 += __shfl_down(s1, off);
        }
        if (l == 0) {
            const float l0 = s0 + Pb[0];
            const float l1 = s1 + Pb[1];
            const int pred = (l1 > l0) ? 1 : 0;
            const float m  = fmaxf(l0, l1);
            const float lse = m + logf(expf(l0 - m) + expf(l1 - m));
            const int lab = labels[b];
            out[b]         = (float)pred;
            out[BATCH + b] = lse - (lab ? l1 : l0);
        }
    }
}

__global__ __launch_bounds__(256) void prep_w(const float* __restrict__ W,
                                              unsigned short* __restrict__ Wh,
                                              unsigned short* __restrict__ Wl)
{
    const int i = blockIdx.x * 256 + threadIdx.x;   // 131072 elems
    const float w = W[i];
    const unsigned short h = f2h(w);
    Wh[i] = h;
    Wl[i] = f2h(w - h2f(h));
}

extern "C" void kernel_launch(void* const* d_in, const int* in_sizes, int n_in,
                              void* d_out, int out_size, void* d_ws, size_t ws_size,
                              hipStream_t stream)
{
    const int*   token_ids = (const int*)d_in[0];
    const int*   labels    = (const int*)d_in[1];
    const float* emb       = (const float*)d_in[2];
    const float* W_w       = (const float*)d_in[3];
    const float* W_b       = (const float*)d_in[4];
    const float* P_w       = (const float*)d_in[5];
    const float* P_b       = (const float*)d_in[6];
    float*       out       = (float*)d_out;

    unsigned short* Ah_buf = (unsigned short*)d_ws;
    unsigned short* Al_buf = Ah_buf + (size_t)131072 * 256;
    unsigned short* Bh_buf = Al_buf + (size_t)131072 * 256;
    unsigned short* Bl_buf = Bh_buf + (size_t)65536 * 256;
    unsigned short* Wh     = Bl_buf + (size_t)65536 * 256;
    unsigned short* Wl     = Wh + 131072;

    const size_t need_wprep = ((size_t)131072 * 256 * 2 + (size_t)65536 * 256 * 2 + 2 * 131072) * 2;
    const bool wprep = ws_size >= need_wprep;

    if (wprep) prep_w<<<512, 256, 0, stream>>>(W_w, Wh, Wl);

    int R = 131072;
    const unsigned short *inh = nullptr, *inl = nullptr;
    for (int lv = 1; lv <= 5; ++lv) {
        unsigned short* yh = (lv & 1) ? Ah_buf : Bh_buf;
        unsigned short* yl = (lv & 1) ? Al_buf : Bl_buf;
        dim3 grid((R / BM) * 2);     // x2 col-blocks; always % 8 == 0
        if (lv == 1) {
            if (wprep) gemm_tree<1,1><<<grid, 256, 0, stream>>>(nullptr, nullptr, Wh, Wl, W_w, W_b, yh, yl, token_ids, emb);
            else       gemm_tree<1,0><<<grid, 256, 0, stream>>>(nullptr, nullptr, Wh, Wl, W_w, W_b, yh, yl, token_ids, emb);
        } else {
            if (wprep) gemm_tree<0,1><<<grid, 256, 0, stream>>>(inh, inl, Wh, Wl, W_w, W_b, yh, yl, nullptr, nullptr);
            else       gemm_tree<0,0><<<grid, 256, 0, stream>>>(inh, inl, Wh, Wl, W_w, W_b, yh, yl, nullptr, nullptr);
        }
        inh = yh; inl = yl; R >>= 1;
    }

    if (wprep) tail_kernel<1><<<BATCH, 256, 0, stream>>>(inh, inl, Wh, Wl, W_w, W_b, P_w, P_b, labels, out);
    else       tail_kernel<0><<<BATCH, 256, 0, stream>>>(inh, inl, Wh, Wl, W_w, W_b, P_w, P_b, labels, out);
}